// Round 15
// baseline (112.572 us; speedup 1.0000x reference)
//
#include <hip/hip_runtime.h>
#include <hip/hip_bf16.h>

#define SQ 4096
#define SKK 4096
#define DIN 768
#define AHS 384
#define NHEAD 12
#define HD 32

typedef __attribute__((ext_vector_type(8))) short bf16x8;
typedef __attribute__((ext_vector_type(4))) float f32x4;
typedef __attribute__((ext_vector_type(4))) unsigned int u32x4;

#define LOG2E 1.4426950408889634f
// log2(e)/sqrt(32): folds the 1/sqrt(d) score scale and exp->exp2 into Q.
#define QSCALE 0.25503486168652855f

// async global->LDS, 16B per lane, linear dest (wave-uniform base + lane*16)
#define GLD16(gp, lp) __builtin_amdgcn_global_load_lds( \
    (const __attribute__((address_space(1))) void*)(gp), \
    (__attribute__((address_space(3))) void*)(lp), 16, 0, 0)

__device__ __forceinline__ unsigned short bf16_rn(float x){
  unsigned int u = __float_as_uint(x);
  unsigned int r = u + 0x7fffu + ((u>>16)&1u);
  return (unsigned short)(r>>16);
}
__device__ __forceinline__ float bf16_f(unsigned short h){
  return __uint_as_float(((unsigned int)h)<<16);
}
__device__ __forceinline__ float fexp2(float x){
#if __has_builtin(__builtin_amdgcn_exp2f)
  return __builtin_amdgcn_exp2f(x);      // bare v_exp_f32
#else
  float r; asm("v_exp_f32 %0, %1" : "=v"(r) : "v"(x)); return r;
#endif
}

// ---------------- EM = e^mask ----------------
__global__ void em_kernel(const float* __restrict__ mask, unsigned short* __restrict__ EMB){
  int idx = blockIdx.x*256 + threadIdx.x;
  if (idx < SKK) EMB[idx] = bf16_rn(__expf(mask[idx]));
}

// ---------------- prep2: W -> W^T hi/lo via LDS transpose (coalesced stores) ----------------
__global__ __launch_bounds__(256) void prep2_kernel(
    const float* __restrict__ Wq, const float* __restrict__ Wk, const float* __restrict__ Wv,
    unsigned short* __restrict__ Wthi, unsigned short* __restrict__ Wtlo)
{
  const int z = blockIdx.z;
  const float* W = (z==0)?Wq:((z==1)?Wk:Wv);
  const int k0 = blockIdx.x*64, n0 = blockIdx.y*64;
  const int tid = threadIdx.x;

  __shared__ float T[64][65];

  const int kr = tid>>2, nc = (tid&3)*16;
  const float* src = W + (size_t)(k0+kr)*AHS + n0 + nc;
  #pragma unroll
  for (int p=0; p<4; ++p){
    f32x4 v = *(const f32x4*)(src + p*4);
    T[kr][nc + p*4 + 0] = v[0];
    T[kr][nc + p*4 + 1] = v[1];
    T[kr][nc + p*4 + 2] = v[2];
    T[kr][nc + p*4 + 3] = v[3];
  }
  __syncthreads();

  const int nr = tid>>2, ks = (tid&3)*16;
  unsigned short* dh = Wthi + (size_t)(z*AHS + n0 + nr)*DIN + k0 + ks;
  unsigned short* dl = Wtlo + (size_t)(z*AHS + n0 + nr)*DIN + k0 + ks;
  #pragma unroll
  for (int half=0; half<2; ++half){
    bf16x8 hv, lv;
    #pragma unroll
    for (int j=0; j<8; ++j){
      float v = T[ks + half*8 + j][nr];
      unsigned short hh = bf16_rn(v);
      hv[j] = (short)hh;
      lv[j] = (short)bf16_rn(v - bf16_f(hh));
    }
    *(bf16x8*)(dh + half*8) = hv;
    *(bf16x8*)(dl + half*8) = lv;
  }
}

// ---------------- proj7: 128x128 tile, 8 waves; A reg-staged, B via GLD16 ----------------
// Grid 288 (= 8 XCD x 36, all co-resident at 2 blocks/CU), XCD-chunked with m
// fastest so each XCD's B panel stays L2-resident. B (pre-converted bf16 W^T)
// is staged by global_load_lds with the XOR chunk-swizzle applied to the
// per-lane GLOBAL source (LDS dest linear) -> stored layout identical to the
// reg-staged version; fragment reads (fidx) unchanged. 3-term hi/lo numerics
// identical to round-12 (REQUIRED; see round-13 post-mortem).
// z=0: Q (scaled log2e/sqrt32) hi/lo HEAD-MAJOR; z=1: K hi/lo HEAD-MAJOR;
// z=2: V bf16 hi-only, pre-scaled by EM, TRANSPOSED [AHS][SKK]
__global__ __launch_bounds__(512,2) void proj7_kernel(
    const float* __restrict__ Xh, const float* __restrict__ Xe,
    const unsigned short* __restrict__ Wthi, const unsigned short* __restrict__ Wtlo,
    const float* __restrict__ bq, const float* __restrict__ bk, const float* __restrict__ bv,
    const unsigned short* __restrict__ EMB,
    unsigned short* __restrict__ Qhi, unsigned short* __restrict__ Qlo,
    unsigned short* __restrict__ Khi, unsigned short* __restrict__ Klo,
    unsigned short* __restrict__ Vt)
{
  const int bid = blockIdx.x;
  const int logical = (bid & 7)*36 + (bid >> 3);   // 288 = 8 XCD x 36
  const int mb = logical & 31;                      // m fastest within chunk
  const int rest = logical >> 5;
  const int nb = rest % 3, z = rest / 3;

  const float* A = (z==0) ? Xh : Xe;
  const unsigned short* Bh = Wthi + (size_t)z*(DIN*AHS);
  const unsigned short* Bl = Wtlo + (size_t)z*(DIN*AHS);
  const float* bias = (z==0) ? bq : ((z==1) ? bk : bv);

  const int m0 = mb*128;
  const int n0 = nb*128;
  const int tid = threadIdx.x;
  const int w = tid>>6, lane = tid&63;
  const int lm = lane&15, g = lane>>4;
  const int wm = w>>1, wn = w&1;   // 4m x 2n waves, wave tile 32x64

  // SH: [buf(2)][sel(4)][4096 shorts]; sel 0=Ah 1=Al 2=Bh 3=Bl. 64KB.
  __shared__ __align__(16) unsigned short SH[32768];

  const int srow = tid>>2, scn = tid&3;
  const int swz = (srow>>1)&3;
  const int sidx = srow*32 + ((scn ^ swz)<<3);      // A chunk-swizzled write
  const float* pA = A + (size_t)(m0 + srow)*DIN + scn*8;
  // B: pre-swizzled global source, linear LDS dest via GLD16
  const unsigned short* gBh = Bh + (size_t)(n0 + srow)*DIN + ((scn ^ swz)<<3);
  const unsigned short* gBl = Bl + (size_t)(n0 + srow)*DIN + ((scn ^ swz)<<3);

  f32x4 xa0, xa1;
  auto sloadA = [&](int kk){
    xa0 = *(const f32x4*)(pA + kk);
    xa1 = *(const f32x4*)(pA + kk + 4);
  };
  auto stageB = [&](int b, int kk){
    GLD16(gBh + kk, &SH[b*16384 + 2*4096 + w*512]);
    if (z != 2) GLD16(gBl + kk, &SH[b*16384 + 3*4096 + w*512]);
  };
  auto swriteA = [&](int b){
    float xx[8] = {xa0[0],xa0[1],xa0[2],xa0[3],xa1[0],xa1[1],xa1[2],xa1[3]};
    unsigned int hw[4];
    #pragma unroll
    for (int p=0;p<4;++p)
      asm("v_cvt_pk_bf16_f32 %0, %1, %2" : "=v"(hw[p]) : "v"(xx[2*p]), "v"(xx[2*p+1]));
    u32x4 ra = {hw[0],hw[1],hw[2],hw[3]};
    *(u32x4*)&SH[b*16384 + 0*4096 + sidx] = ra;
    if (z != 2){
      unsigned int lw[4];
      #pragma unroll
      for (int p=0;p<4;++p){
        float h0 = __uint_as_float(hw[p]<<16);
        float h1 = __uint_as_float(hw[p] & 0xffff0000u);
        float l0 = xx[2*p] - h0, l1 = xx[2*p+1] - h1;
        asm("v_cvt_pk_bf16_f32 %0, %1, %2" : "=v"(lw[p]) : "v"(l0), "v"(l1));
      }
      u32x4 rla = {lw[0],lw[1],lw[2],lw[3]};
      *(u32x4*)&SH[b*16384 + 1*4096 + sidx] = rla;
    }
  };

  f32x4 acc[2][4];
  #pragma unroll
  for (int mi=0;mi<2;++mi)
    #pragma unroll
    for (int ni=0;ni<4;++ni) acc[mi][ni] = (f32x4){0.f,0.f,0.f,0.f};

  auto fidx = [&](int row)->int{ return row*32 + ((g ^ ((row>>1)&3))<<3); };

  stageB(0, 0); sloadA(0); swriteA(0); __syncthreads();
  int cur = 0;

  const int NKS = DIN/32;  // 24
  for (int t=0; t<NKS; ++t){
    if (t+1 < NKS){
      stageB(cur^1, (t+1)*32);   // async DMA, drained at this step's barrier
      sloadA((t+1)*32);
    }

    const unsigned short* AhL = &SH[cur*16384 + 0*4096];
    const unsigned short* AlL = &SH[cur*16384 + 1*4096];
    const unsigned short* BhL = &SH[cur*16384 + 2*4096];
    const unsigned short* BlL = &SH[cur*16384 + 3*4096];

    bf16x8 a0h = *(const bf16x8*)&AhL[fidx(wm*32 + lm)];
    bf16x8 a1h = *(const bf16x8*)&AhL[fidx(wm*32 + 16 + lm)];
    bf16x8 a0l, a1l;
    if (z != 2){
      a0l = *(const bf16x8*)&AlL[fidx(wm*32 + lm)];
      a1l = *(const bf16x8*)&AlL[fidx(wm*32 + 16 + lm)];
    }
    __builtin_amdgcn_s_setprio(1);
    #pragma unroll
    for (int ni=0; ni<4; ++ni){
      bf16x8 bh = *(const bf16x8*)&BhL[fidx(wn*64 + ni*16 + lm)];
      acc[0][ni] = __builtin_amdgcn_mfma_f32_16x16x32_bf16(a0h, bh, acc[0][ni], 0,0,0);
      acc[1][ni] = __builtin_amdgcn_mfma_f32_16x16x32_bf16(a1h, bh, acc[1][ni], 0,0,0);
      if (z != 2){
        bf16x8 bl = *(const bf16x8*)&BlL[fidx(wn*64 + ni*16 + lm)];
        acc[0][ni] = __builtin_amdgcn_mfma_f32_16x16x32_bf16(a0h, bl, acc[0][ni], 0,0,0);
        acc[1][ni] = __builtin_amdgcn_mfma_f32_16x16x32_bf16(a1h, bl, acc[1][ni], 0,0,0);
        acc[0][ni] = __builtin_amdgcn_mfma_f32_16x16x32_bf16(a0l, bh, acc[0][ni], 0,0,0);
        acc[1][ni] = __builtin_amdgcn_mfma_f32_16x16x32_bf16(a1l, bh, acc[1][ni], 0,0,0);
      }
    }
    __builtin_amdgcn_s_setprio(0);

    if (t+1 < NKS) swriteA(cur^1);
    __syncthreads();
    cur ^= 1;
  }

  if (z != 2){
    #pragma unroll
    for (int ni=0; ni<4; ++ni){
      int col = n0 + wn*64 + ni*16 + lm;
      float bcol = bias[col];
      int hq = col>>5, d = col&31;
      #pragma unroll
      for (int mi=0; mi<2; ++mi){
        #pragma unroll
        for (int r=0; r<4; ++r){
          int row = m0 + wm*32 + mi*16 + g*4 + r;
          float v = acc[mi][ni][r] + bcol;
          if (z==0) v *= QSCALE;
          unsigned short hh = bf16_rn(v);
          unsigned short ll = bf16_rn(v - bf16_f(hh));
          size_t p = (z==0) ? ((size_t)hq*SQ + row)*HD + d
                            : ((size_t)hq*SKK + row)*HD + d;
          if (z==0){ Qhi[p]=hh; Qlo[p]=ll; } else { Khi[p]=hh; Klo[p]=ll; }
        }
      }
    }
  } else {
    // V: scale rows by EM, LDS transpose, coalesced 16B writes.
    #pragma unroll
    for (int ni=0; ni<4; ++ni){
      int lcol = wn*64 + ni*16 + lm;
      float bcol = bias[n0 + lcol];
      #pragma unroll
      for (int mi=0; mi<2; ++mi){
        #pragma unroll
        for (int r=0; r<4; ++r){
          int lrow = wm*32 + mi*16 + g*4 + r;
          float emf = bf16_f(EMB[m0 + lrow]);
          SH[lcol*128 + (lrow ^ ((lcol&7)<<3))] = bf16_rn((acc[mi][ni][r] + bcol) * emf);
        }
      }
    }
    __syncthreads();
    #pragma unroll
    for (int p=0; p<4; ++p){
      int c = tid>>2, rc = (tid&3)*8 + p*32;
      bf16x8 vv = *(const bf16x8*)&SH[c*128 + (rc ^ ((c&7)<<3))];
      *(bf16x8*)(Vt + (size_t)(n0 + c)*SKK + m0 + rc) = vv;
    }
  }
}

// ---------------- fused flash attention: global_load_lds K/V, in-register P ----------------
// Verbatim round-12/14 structure (3-term scores, no online max, EM-folded mask).
__global__ __launch_bounds__(256) void attn_kernel(
    const unsigned short* __restrict__ Qhi, const unsigned short* __restrict__ Qlo,
    const unsigned short* __restrict__ Khi, const unsigned short* __restrict__ Klo,
    const unsigned short* __restrict__ Vt, const unsigned short* __restrict__ EMB,
    float* __restrict__ opart, float* __restrict__ lpart,
    int nkt, int direct, int chunk)
{
  const int bid = blockIdx.x;
  const int logical = (bid & 7)*chunk + (bid >> 3);
  const int qt = logical & 63;
  const int rest = logical >> 6;
  const int h = rest % NHEAD, sp = rest / NHEAD;

  const int tid = threadIdx.x;
  const int w = tid>>6, lane = tid&63;
  const int lm = lane&15, g = lane>>4;
  const int qrow = qt*64 + w*16 + lm;
  const int kbeg = sp*nkt*64;

  __shared__ unsigned short KhL[2][2048];
  __shared__ unsigned short KlL[2][2048];
  __shared__ unsigned short VL [2][2048];

  const int krow_l = 16*w + (lane>>2);
  const int ksw_l = ((krow_l>>1)&1) ^ (((krow_l>>3)&1)<<1);
  const unsigned short* gKh = Khi + (size_t)h*SKK*HD
                            + (size_t)(kbeg + krow_l)*HD + (((lane&3)^ksw_l)<<3);
  const unsigned short* gKl = Klo + (size_t)h*SKK*HD
                            + (size_t)(kbeg + krow_l)*HD + (((lane&3)^ksw_l)<<3);
  const int vrow_l = 8*w + (lane>>3);
  const unsigned short* gV = Vt + (size_t)(h*HD + vrow_l)*SKK + kbeg
                           + (((lane&7)^(lane>>3))<<3);
  const unsigned short* pEM = EMB + kbeg + g*8;

  const int krs = ((lm>>2)<<3) + (lm&3);
  const int rsw = ((krs>>1)&1) ^ (((krs>>3)&1)<<1);
  const int kread0 = krs*32 + ((g ^ rsw)<<3);

  int vr[4];
  vr[0] = (lm*64      + g*8)      ^ ((lm&7)<<3);
  vr[1] = (lm*64      + 32 + g*8) ^ ((lm&7)<<3);
  vr[2] = ((lm+16)*64 + g*8)      ^ ((lm&7)<<3);
  vr[3] = ((lm+16)*64 + 32 + g*8) ^ ((lm&7)<<3);

  bf16x8 qh = *(const bf16x8*)(Qhi + ((size_t)h*SQ + qrow)*HD + g*8);
  bf16x8 ql = *(const bf16x8*)(Qlo + ((size_t)h*SQ + qrow)*HD + g*8);

  f32x4 o0 = {0.f,0.f,0.f,0.f}, o1 = {0.f,0.f,0.f,0.f};
  f32x4 lacc = {0.f,0.f,0.f,0.f};

  GLD16(gKh, &KhL[0][w*512]);
  GLD16(gKl, &KlL[0][w*512]);
  GLD16(gV,  &VL [0][w*512]);
  __syncthreads();

  #pragma unroll 2
  for (int t=0; t<nkt; ++t){
    const int cur = t&1;

    if (t+1 < nkt){
      gKh += 64*HD; gKl += 64*HD; gV += 64;
      GLD16(gKh, &KhL[cur^1][w*512]);
      GLD16(gKl, &KlL[cur^1][w*512]);
      GLD16(gV,  &VL [cur^1][w*512]);
    }

    bf16x8 em0 = *(const bf16x8*)(pEM);
    bf16x8 em1 = *(const bf16x8*)(pEM + 32);
    pEM += 64;

    unsigned int wds[8];
    #pragma unroll
    for (int ks=0; ks<4; ++ks){
      const int kidx = kread0 + (ks&1)*128 + (ks>>1)*1024;
      bf16x8 kh = *(const bf16x8*)(&KhL[cur][kidx]);
      bf16x8 kl = *(const bf16x8*)(&KlL[cur][kidx]);
      f32x4 a = {0.f,0.f,0.f,0.f};
      __builtin_amdgcn_s_setprio(1);
      a = __builtin_amdgcn_mfma_f32_16x16x32_bf16(kh, qh, a, 0,0,0);
      a = __builtin_amdgcn_mfma_f32_16x16x32_bf16(kh, ql, a, 0,0,0);
      a = __builtin_amdgcn_mfma_f32_16x16x32_bf16(kl, qh, a, 0,0,0);
      __builtin_amdgcn_s_setprio(0);
      float p0 = fexp2(a[0]);
      float p1 = fexp2(a[1]);
      float p2 = fexp2(a[2]);
      float p3 = fexp2(a[3]);
      asm("v_cvt_pk_bf16_f32 %0, %1, %2" : "=v"(wds[ks*2])   : "v"(p0), "v"(p1));
      asm("v_cvt_pk_bf16_f32 %0, %1, %2" : "=v"(wds[ks*2+1]) : "v"(p2), "v"(p3));
    }
    u32x4 w0v = {wds[0], wds[1], wds[2], wds[3]};
    u32x4 w1v = {wds[4], wds[5], wds[6], wds[7]};
    bf16x8 pa0 = __builtin_bit_cast(bf16x8, w0v);
    bf16x8 pa1 = __builtin_bit_cast(bf16x8, w1v);

    bf16x8 v00 = *(const bf16x8*)(&VL[cur][vr[0]]);
    bf16x8 v01 = *(const bf16x8*)(&VL[cur][vr[1]]);
    bf16x8 v10 = *(const bf16x8*)(&VL[cur][vr[2]]);
    bf16x8 v11 = *(const bf16x8*)(&VL[cur][vr[3]]);
    __builtin_amdgcn_s_setprio(1);
    o0   = __builtin_amdgcn_mfma_f32_16x16x32_bf16(pa0, v00, o0,   0,0,0);
    o1   = __builtin_amdgcn_mfma_f32_16x16x32_bf16(pa0, v10, o1,   0,0,0);
    lacc = __builtin_amdgcn_mfma_f32_16x16x32_bf16(pa0, em0, lacc, 0,0,0);
    o0   = __builtin_amdgcn_mfma_f32_16x16x32_bf16(pa1, v01, o0,   0,0,0);
    o1   = __builtin_amdgcn_mfma_f32_16x16x32_bf16(pa1, v11, o1,   0,0,0);
    lacc = __builtin_amdgcn_mfma_f32_16x16x32_bf16(pa1, em1, lacc, 0,0,0);
    __builtin_amdgcn_s_setprio(0);

    __syncthreads();
  }

  if (direct){
    #pragma unroll
    for (int r=0;r<4;++r){
      float inv = 1.0f / lacc[r];
      int row = qt*64 + w*16 + g*4 + r;
      opart[(size_t)row*AHS + h*HD + lm]      = o0[r]*inv;
      opart[(size_t)row*AHS + h*HD + 16 + lm] = o1[r]*inv;
    }
  } else {
    #pragma unroll
    for (int r=0;r<4;++r){
      int row = qt*64 + w*16 + g*4 + r;
      opart[((size_t)sp*SQ + row)*AHS + h*HD + lm]      = o0[r];
      opart[((size_t)sp*SQ + row)*AHS + h*HD + 16 + lm] = o1[r];
    }
    if (lm == 0){
      #pragma unroll
      for (int r=0;r<4;++r){
        int row = qt*64 + w*16 + g*4 + r;
        lpart[((size_t)sp*NHEAD + h)*SQ + row] = lacc[r];
      }
    }
  }
}

// ---------------- merge partial splits: plain sums (shared scale) ----------------
__global__ void merge_kernel(const float* __restrict__ opart,
                             const float* __restrict__ lpart,
                             float* __restrict__ out, int S){
  int idx = blockIdx.x*256 + threadIdx.x;
  if (idx >= SQ*AHS) return;
  int row = idx/AHS, c = idx - row*AHS;
  int h = c >> 5;
  float num = 0.f, den = 0.f;
  for (int s=0; s<S; ++s){
    num += opart[((size_t)s*SQ + row)*AHS + c];
    den += lpart[((size_t)s*NHEAD + h)*SQ + row];
  }
  out[idx] = num/den;
}

extern "C" void kernel_launch(void* const* d_in, const int* in_sizes, int n_in,
                              void* d_out, int out_size, void* d_ws, size_t ws_size,
                              hipStream_t stream) {
  const float* Xh   = (const float*)d_in[0];
  const float* Xe   = (const float*)d_in[1];
  const float* mask = (const float*)d_in[2];
  const float* Wq   = (const float*)d_in[3];
  const float* bq   = (const float*)d_in[4];
  const float* Wk   = (const float*)d_in[5];
  const float* bk   = (const float*)d_in[6];
  const float* Wv   = (const float*)d_in[7];
  const float* bv   = (const float*)d_in[8];
  float* out = (float*)d_out;

  char* ws = (char*)d_ws;
  auto al256 = [](size_t b)->size_t{ return (b + 255) & ~(size_t)255; };
  size_t off = 0;
  auto alloc = [&](size_t bytes)->void*{ void* p = ws + off; off += al256(bytes); return p; };

  unsigned short* Wthi = (unsigned short*)alloc((size_t)3*DIN*AHS*2);
  unsigned short* Wtlo = (unsigned short*)alloc((size_t)3*DIN*AHS*2);
  unsigned short* EMB  = (unsigned short*)alloc((size_t)SKK*2);
  unsigned short* Qhi  = (unsigned short*)alloc((size_t)NHEAD*SQ*HD*2);
  unsigned short* Qlo  = (unsigned short*)alloc((size_t)NHEAD*SQ*HD*2);
  unsigned short* Khi  = (unsigned short*)alloc((size_t)NHEAD*SKK*HD*2);
  unsigned short* Klo  = (unsigned short*)alloc((size_t)NHEAD*SKK*HD*2);
  unsigned short* Vt   = (unsigned short*)alloc((size_t)AHS*SKK*2);
  const size_t base_end = off;

  const size_t OB = al256((size_t)SQ*AHS*4);
  const size_t MB = al256((size_t)NHEAD*SQ*4);

  auto fits = [&](int S)->bool{
    return base_end + (size_t)S*OB + (size_t)S*MB + 8192 <= ws_size;
  };

  int S = 1, direct = 0;
  if      (fits(2)) S = 2;
  else if (fits(1)) S = 1;
  else { S = 1; direct = 1; }

  char* ureg = ws + base_end;
  float *opart, *lpart;
  if (!direct){
    opart = (float*)(ureg);
    lpart = (float*)(ureg + (size_t)S*OB);
  } else {
    opart = out; lpart = (float*)ws;
  }

  {
    em_kernel<<<(SKK+255)/256, 256, 0, stream>>>(mask, EMB);
    dim3 grid(DIN/64, AHS/64, 3);
    prep2_kernel<<<grid, 256, 0, stream>>>(Wq, Wk, Wv, Wthi, Wtlo);
  }
  {
    proj7_kernel<<<288, 512, 0, stream>>>(Xh, Xe, Wthi, Wtlo,
                                          bq, bk, bv, EMB, Qhi, Qlo, Khi, Klo, Vt);
  }
  {
    int nblk = 64*NHEAD*S;
    int nkt = (SKK/64)/S;
    attn_kernel<<<nblk, 256, 0, stream>>>(Qhi, Qlo, Khi, Klo, Vt, EMB,
                                          opart, lpart, nkt, direct, nblk/8);
  }
  if (!direct){
    int n = SQ*AHS;
    merge_kernel<<<(n+255)/256, 256, 0, stream>>>(opart, lpart, out, S);
  }
}

// Round 16
// 105.912 us; speedup vs baseline: 1.0629x; 1.0629x over previous
//
#include <hip/hip_runtime.h>
#include <hip/hip_bf16.h>

#define SQ 4096
#define SKK 4096
#define DIN 768
#define AHS 384
#define NHEAD 12
#define HD 32

typedef __attribute__((ext_vector_type(8))) short bf16x8;
typedef __attribute__((ext_vector_type(4))) float f32x4;
typedef __attribute__((ext_vector_type(4))) unsigned int u32x4;

#define LOG2E 1.4426950408889634f
// log2(e)/sqrt(32): folds the 1/sqrt(d) score scale and exp->exp2 into Q.
#define QSCALE 0.25503486168652855f

// async global->LDS, 16B per lane, linear dest (wave-uniform base + lane*16)
#define GLD16(gp, lp) __builtin_amdgcn_global_load_lds( \
    (const __attribute__((address_space(1))) void*)(gp), \
    (__attribute__((address_space(3))) void*)(lp), 16, 0, 0)

__device__ __forceinline__ unsigned short bf16_rn(float x){
  unsigned int u = __float_as_uint(x);
  unsigned int r = u + 0x7fffu + ((u>>16)&1u);
  return (unsigned short)(r>>16);
}
__device__ __forceinline__ float bf16_f(unsigned short h){
  return __uint_as_float(((unsigned int)h)<<16);
}
__device__ __forceinline__ float fexp2(float x){
#if __has_builtin(__builtin_amdgcn_exp2f)
  return __builtin_amdgcn_exp2f(x);      // bare v_exp_f32
#else
  float r; asm("v_exp_f32 %0, %1" : "=v"(r) : "v"(x)); return r;
#endif
}

// ---------------- prep2: W -> W^T hi/lo via LDS transpose; EM = e^mask fused ----------------
__global__ __launch_bounds__(256) void prep2_kernel(
    const float* __restrict__ Wq, const float* __restrict__ Wk, const float* __restrict__ Wv,
    const float* __restrict__ mask,
    unsigned short* __restrict__ Wthi, unsigned short* __restrict__ Wtlo,
    unsigned short* __restrict__ EMB)
{
  // fused EM (grid has 216*256 = 55296 threads >= SKK)
  {
    int lid = ((blockIdx.z*gridDim.y + blockIdx.y)*gridDim.x + blockIdx.x)*256 + threadIdx.x;
    if (lid < SKK) EMB[lid] = bf16_rn(__expf(mask[lid]));
  }

  const int z = blockIdx.z;
  const float* W = (z==0)?Wq:((z==1)?Wk:Wv);
  const int k0 = blockIdx.x*64, n0 = blockIdx.y*64;
  const int tid = threadIdx.x;

  __shared__ float T[64][65];

  const int kr = tid>>2, nc = (tid&3)*16;
  const float* src = W + (size_t)(k0+kr)*AHS + n0 + nc;
  #pragma unroll
  for (int p=0; p<4; ++p){
    f32x4 v = *(const f32x4*)(src + p*4);
    T[kr][nc + p*4 + 0] = v[0];
    T[kr][nc + p*4 + 1] = v[1];
    T[kr][nc + p*4 + 2] = v[2];
    T[kr][nc + p*4 + 3] = v[3];
  }
  __syncthreads();

  const int nr = tid>>2, ks = (tid&3)*16;
  unsigned short* dh = Wthi + (size_t)(z*AHS + n0 + nr)*DIN + k0 + ks;
  unsigned short* dl = Wtlo + (size_t)(z*AHS + n0 + nr)*DIN + k0 + ks;
  #pragma unroll
  for (int half=0; half<2; ++half){
    bf16x8 hv, lv;
    #pragma unroll
    for (int j=0; j<8; ++j){
      float v = T[ks + half*8 + j][nr];
      unsigned short hh = bf16_rn(v);
      hv[j] = (short)hh;
      lv[j] = (short)bf16_rn(v - bf16_f(hh));
    }
    *(bf16x8*)(dh + half*8) = hv;
    *(bf16x8*)(dl + half*8) = lv;
  }
}

// ---------------- proj5: 128x96 tile, 8 waves, LDS dbuf, fused X split ----------------
// Grid 384 (= 8 XCD x 48, all co-resident at 2 blocks/CU), XCD-chunked with m
// fastest so each XCD's B panel (96x768 hi/lo ~ 294 KB) stays L2-resident.
// 3-term hi/lo numerics identical to round-12 (REQUIRED; round-13 post-mortem).
// z=0: Q (scaled log2e/sqrt32) hi/lo HEAD-MAJOR; z=1: K hi/lo HEAD-MAJOR;
// z=2: V bf16 hi-only, pre-scaled by EM, TRANSPOSED [AHS][SKK]
__global__ __launch_bounds__(512,2) void proj5_kernel(
    const float* __restrict__ Xh, const float* __restrict__ Xe,
    const unsigned short* __restrict__ Wthi, const unsigned short* __restrict__ Wtlo,
    const float* __restrict__ bq, const float* __restrict__ bk, const float* __restrict__ bv,
    const unsigned short* __restrict__ EMB,
    unsigned short* __restrict__ Qhi, unsigned short* __restrict__ Qlo,
    unsigned short* __restrict__ Khi, unsigned short* __restrict__ Klo,
    unsigned short* __restrict__ Vt)
{
  const int bid = blockIdx.x;
  const int logical = (bid & 7)*48 + (bid >> 3);   // 384 = 8 XCD x 48
  const int mb = logical & 31;                      // m fastest within chunk
  const int rest = logical >> 5;
  const int nb = rest & 3, z = rest >> 2;

  const float* A = (z==0) ? Xh : Xe;
  const unsigned short* Bh = Wthi + (size_t)z*(DIN*AHS);
  const unsigned short* Bl = Wtlo + (size_t)z*(DIN*AHS);
  const float* bias = (z==0) ? bq : ((z==1) ? bk : bv);

  const int m0 = mb*128;
  const int n0 = nb*96;
  const int tid = threadIdx.x;
  const int w = tid>>6, lane = tid&63;
  const int lm = lane&15, g = lane>>4;
  const int wm = w>>1, wn = w&1;   // 4m x 2n waves, wave tile 32x48

  __shared__ __align__(16) unsigned short SH[32768];

  const int srow = tid>>2, scn = tid&3;
  const int sidx = srow*32 + ((scn ^ ((srow>>1)&3))<<3);  // chunk-swizzled
  const float* pA = A + (size_t)(m0 + srow)*DIN + scn*8;
  const size_t gb = (size_t)(n0 + srow)*DIN + scn*8;
  const bool doB = (srow < 96);

  f32x4 xa0, xa1; u32x4 rb, rlb;
  auto sload = [&](int kk){
    xa0 = *(const f32x4*)(pA + kk);
    xa1 = *(const f32x4*)(pA + kk + 4);
    if (doB){
      rb = *(const u32x4*)(Bh + gb + kk);
      if (z != 2) rlb = *(const u32x4*)(Bl + gb + kk);
    }
  };
  auto swrite = [&](int b){
    float xx[8] = {xa0[0],xa0[1],xa0[2],xa0[3],xa1[0],xa1[1],xa1[2],xa1[3]};
    unsigned int hw[4];
    #pragma unroll
    for (int p=0;p<4;++p)
      asm("v_cvt_pk_bf16_f32 %0, %1, %2" : "=v"(hw[p]) : "v"(xx[2*p]), "v"(xx[2*p+1]));
    u32x4 ra = {hw[0],hw[1],hw[2],hw[3]};
    *(u32x4*)&SH[b*16384 + 0*4096 + sidx] = ra;
    if (doB) *(u32x4*)&SH[b*16384 + 2*4096 + sidx] = rb;
    if (z != 2){
      unsigned int lw[4];
      #pragma unroll
      for (int p=0;p<4;++p){
        float h0 = __uint_as_float(hw[p]<<16);
        float h1 = __uint_as_float(hw[p] & 0xffff0000u);
        float l0 = xx[2*p] - h0, l1 = xx[2*p+1] - h1;
        asm("v_cvt_pk_bf16_f32 %0, %1, %2" : "=v"(lw[p]) : "v"(l0), "v"(l1));
      }
      u32x4 rla = {lw[0],lw[1],lw[2],lw[3]};
      *(u32x4*)&SH[b*16384 + 1*4096 + sidx] = rla;
      if (doB) *(u32x4*)&SH[b*16384 + 3*4096 + sidx] = rlb;
    }
  };

  f32x4 acc[2][3];
  #pragma unroll
  for (int mi=0;mi<2;++mi)
    #pragma unroll
    for (int ni=0;ni<3;++ni) acc[mi][ni] = (f32x4){0.f,0.f,0.f,0.f};

  auto fidx = [&](int row)->int{ return row*32 + ((g ^ ((row>>1)&3))<<3); };

  sload(0); swrite(0); __syncthreads();
  int cur = 0;

  const int NKS = DIN/32;  // 24
  for (int t=0; t<NKS; ++t){
    if (t+1 < NKS) sload((t+1)*32);

    const unsigned short* AhL = &SH[cur*16384 + 0*4096];
    const unsigned short* AlL = &SH[cur*16384 + 1*4096];
    const unsigned short* BhL = &SH[cur*16384 + 2*4096];
    const unsigned short* BlL = &SH[cur*16384 + 3*4096];

    bf16x8 a0h = *(const bf16x8*)&AhL[fidx(wm*32 + lm)];
    bf16x8 a1h = *(const bf16x8*)&AhL[fidx(wm*32 + 16 + lm)];
    bf16x8 a0l, a1l;
    if (z != 2){
      a0l = *(const bf16x8*)&AlL[fidx(wm*32 + lm)];
      a1l = *(const bf16x8*)&AlL[fidx(wm*32 + 16 + lm)];
    }
    __builtin_amdgcn_s_setprio(1);
    #pragma unroll
    for (int ni=0; ni<3; ++ni){
      bf16x8 bh = *(const bf16x8*)&BhL[fidx(wn*48 + ni*16 + lm)];
      acc[0][ni] = __builtin_amdgcn_mfma_f32_16x16x32_bf16(a0h, bh, acc[0][ni], 0,0,0);
      acc[1][ni] = __builtin_amdgcn_mfma_f32_16x16x32_bf16(a1h, bh, acc[1][ni], 0,0,0);
      if (z != 2){
        bf16x8 bl = *(const bf16x8*)&BlL[fidx(wn*48 + ni*16 + lm)];
        acc[0][ni] = __builtin_amdgcn_mfma_f32_16x16x32_bf16(a0h, bl, acc[0][ni], 0,0,0);
        acc[1][ni] = __builtin_amdgcn_mfma_f32_16x16x32_bf16(a1h, bl, acc[1][ni], 0,0,0);
        acc[0][ni] = __builtin_amdgcn_mfma_f32_16x16x32_bf16(a0l, bh, acc[0][ni], 0,0,0);
        acc[1][ni] = __builtin_amdgcn_mfma_f32_16x16x32_bf16(a1l, bh, acc[1][ni], 0,0,0);
      }
    }
    __builtin_amdgcn_s_setprio(0);

    if (t+1 < NKS) swrite(cur^1);
    __syncthreads();
    cur ^= 1;
  }

  if (z != 2){
    #pragma unroll
    for (int ni=0; ni<3; ++ni){
      int col = n0 + wn*48 + ni*16 + lm;
      float bcol = bias[col];
      int hq = col>>5, d = col&31;
      #pragma unroll
      for (int mi=0; mi<2; ++mi){
        #pragma unroll
        for (int r=0; r<4; ++r){
          int row = m0 + wm*32 + mi*16 + g*4 + r;
          float v = acc[mi][ni][r] + bcol;
          if (z==0) v *= QSCALE;
          unsigned short hh = bf16_rn(v);
          unsigned short ll = bf16_rn(v - bf16_f(hh));
          size_t p = (z==0) ? ((size_t)hq*SQ + row)*HD + d
                            : ((size_t)hq*SKK + row)*HD + d;
          if (z==0){ Qhi[p]=hh; Qlo[p]=ll; } else { Khi[p]=hh; Klo[p]=ll; }
        }
      }
    }
  } else {
    // V: scale rows by EM, LDS transpose (96 cols x 128 rows), 16B stores.
    #pragma unroll
    for (int ni=0; ni<3; ++ni){
      int lcol = wn*48 + ni*16 + lm;
      float bcol = bias[n0 + lcol];
      #pragma unroll
      for (int mi=0; mi<2; ++mi){
        #pragma unroll
        for (int r=0; r<4; ++r){
          int lrow = wm*32 + mi*16 + g*4 + r;
          float emf = bf16_f(EMB[m0 + lrow]);
          SH[lcol*128 + (lrow ^ ((lcol&7)<<3))] = bf16_rn((acc[mi][ni][r] + bcol) * emf);
        }
      }
    }
    __syncthreads();
    #pragma unroll
    for (int p=0; p<3; ++p){
      int idx = p*512 + tid;
      int c = idx>>4, rc = (idx&15)*8;
      bf16x8 vv = *(const bf16x8*)&SH[c*128 + (rc ^ ((c&7)<<3))];
      *(bf16x8*)(Vt + (size_t)(n0 + c)*SKK + m0 + rc) = vv;
    }
  }
}

// ---------------- fused flash attention: global_load_lds K/V, in-register P ----------------
// Verbatim round-12/14 structure (3-term scores, no online max, EM-folded mask).
__global__ __launch_bounds__(256) void attn_kernel(
    const unsigned short* __restrict__ Qhi, const unsigned short* __restrict__ Qlo,
    const unsigned short* __restrict__ Khi, const unsigned short* __restrict__ Klo,
    const unsigned short* __restrict__ Vt, const unsigned short* __restrict__ EMB,
    float* __restrict__ opart, float* __restrict__ lpart,
    int nkt, int direct, int chunk)
{
  const int bid = blockIdx.x;
  const int logical = (bid & 7)*chunk + (bid >> 3);
  const int qt = logical & 63;
  const int rest = logical >> 6;
  const int h = rest % NHEAD, sp = rest / NHEAD;

  const int tid = threadIdx.x;
  const int w = tid>>6, lane = tid&63;
  const int lm = lane&15, g = lane>>4;
  const int qrow = qt*64 + w*16 + lm;
  const int kbeg = sp*nkt*64;

  __shared__ unsigned short KhL[2][2048];
  __shared__ unsigned short KlL[2][2048];
  __shared__ unsigned short VL [2][2048];

  const int krow_l = 16*w + (lane>>2);
  const int ksw_l = ((krow_l>>1)&1) ^ (((krow_l>>3)&1)<<1);
  const unsigned short* gKh = Khi + (size_t)h*SKK*HD
                            + (size_t)(kbeg + krow_l)*HD + (((lane&3)^ksw_l)<<3);
  const unsigned short* gKl = Klo + (size_t)h*SKK*HD
                            + (size_t)(kbeg + krow_l)*HD + (((lane&3)^ksw_l)<<3);
  const int vrow_l = 8*w + (lane>>3);
  const unsigned short* gV = Vt + (size_t)(h*HD + vrow_l)*SKK + kbeg
                           + (((lane&7)^(lane>>3))<<3);
  const unsigned short* pEM = EMB + kbeg + g*8;

  const int krs = ((lm>>2)<<3) + (lm&3);
  const int rsw = ((krs>>1)&1) ^ (((krs>>3)&1)<<1);
  const int kread0 = krs*32 + ((g ^ rsw)<<3);

  int vr[4];
  vr[0] = (lm*64      + g*8)      ^ ((lm&7)<<3);
  vr[1] = (lm*64      + 32 + g*8) ^ ((lm&7)<<3);
  vr[2] = ((lm+16)*64 + g*8)      ^ ((lm&7)<<3);
  vr[3] = ((lm+16)*64 + 32 + g*8) ^ ((lm&7)<<3);

  bf16x8 qh = *(const bf16x8*)(Qhi + ((size_t)h*SQ + qrow)*HD + g*8);
  bf16x8 ql = *(const bf16x8*)(Qlo + ((size_t)h*SQ + qrow)*HD + g*8);

  f32x4 o0 = {0.f,0.f,0.f,0.f}, o1 = {0.f,0.f,0.f,0.f};
  f32x4 lacc = {0.f,0.f,0.f,0.f};

  GLD16(gKh, &KhL[0][w*512]);
  GLD16(gKl, &KlL[0][w*512]);
  GLD16(gV,  &VL [0][w*512]);
  __syncthreads();

  #pragma unroll 2
  for (int t=0; t<nkt; ++t){
    const int cur = t&1;

    if (t+1 < nkt){
      gKh += 64*HD; gKl += 64*HD; gV += 64;
      GLD16(gKh, &KhL[cur^1][w*512]);
      GLD16(gKl, &KlL[cur^1][w*512]);
      GLD16(gV,  &VL [cur^1][w*512]);
    }

    bf16x8 em0 = *(const bf16x8*)(pEM);
    bf16x8 em1 = *(const bf16x8*)(pEM + 32);
    pEM += 64;

    unsigned int wds[8];
    #pragma unroll
    for (int ks=0; ks<4; ++ks){
      const int kidx = kread0 + (ks&1)*128 + (ks>>1)*1024;
      bf16x8 kh = *(const bf16x8*)(&KhL[cur][kidx]);
      bf16x8 kl = *(const bf16x8*)(&KlL[cur][kidx]);
      f32x4 a = {0.f,0.f,0.f,0.f};
      __builtin_amdgcn_s_setprio(1);
      a = __builtin_amdgcn_mfma_f32_16x16x32_bf16(kh, qh, a, 0,0,0);
      a = __builtin_amdgcn_mfma_f32_16x16x32_bf16(kh, ql, a, 0,0,0);
      a = __builtin_amdgcn_mfma_f32_16x16x32_bf16(kl, qh, a, 0,0,0);
      __builtin_amdgcn_s_setprio(0);
      float p0 = fexp2(a[0]);
      float p1 = fexp2(a[1]);
      float p2 = fexp2(a[2]);
      float p3 = fexp2(a[3]);
      asm("v_cvt_pk_bf16_f32 %0, %1, %2" : "=v"(wds[ks*2])   : "v"(p0), "v"(p1));
      asm("v_cvt_pk_bf16_f32 %0, %1, %2" : "=v"(wds[ks*2+1]) : "v"(p2), "v"(p3));
    }
    u32x4 w0v = {wds[0], wds[1], wds[2], wds[3]};
    u32x4 w1v = {wds[4], wds[5], wds[6], wds[7]};
    bf16x8 pa0 = __builtin_bit_cast(bf16x8, w0v);
    bf16x8 pa1 = __builtin_bit_cast(bf16x8, w1v);

    bf16x8 v00 = *(const bf16x8*)(&VL[cur][vr[0]]);
    bf16x8 v01 = *(const bf16x8*)(&VL[cur][vr[1]]);
    bf16x8 v10 = *(const bf16x8*)(&VL[cur][vr[2]]);
    bf16x8 v11 = *(const bf16x8*)(&VL[cur][vr[3]]);
    __builtin_amdgcn_s_setprio(1);
    o0   = __builtin_amdgcn_mfma_f32_16x16x32_bf16(pa0, v00, o0,   0,0,0);
    o1   = __builtin_amdgcn_mfma_f32_16x16x32_bf16(pa0, v10, o1,   0,0,0);
    lacc = __builtin_amdgcn_mfma_f32_16x16x32_bf16(pa0, em0, lacc, 0,0,0);
    o0   = __builtin_amdgcn_mfma_f32_16x16x32_bf16(pa1, v01, o0,   0,0,0);
    o1   = __builtin_amdgcn_mfma_f32_16x16x32_bf16(pa1, v11, o1,   0,0,0);
    lacc = __builtin_amdgcn_mfma_f32_16x16x32_bf16(pa1, em1, lacc, 0,0,0);
    __builtin_amdgcn_s_setprio(0);

    __syncthreads();
  }

  if (direct){
    #pragma unroll
    for (int r=0;r<4;++r){
      float inv = 1.0f / lacc[r];
      int row = qt*64 + w*16 + g*4 + r;
      opart[(size_t)row*AHS + h*HD + lm]      = o0[r]*inv;
      opart[(size_t)row*AHS + h*HD + 16 + lm] = o1[r]*inv;
    }
  } else {
    #pragma unroll
    for (int r=0;r<4;++r){
      int row = qt*64 + w*16 + g*4 + r;
      opart[((size_t)sp*SQ + row)*AHS + h*HD + lm]      = o0[r];
      opart[((size_t)sp*SQ + row)*AHS + h*HD + 16 + lm] = o1[r];
    }
    if (lm == 0){
      #pragma unroll
      for (int r=0;r<4;++r){
        int row = qt*64 + w*16 + g*4 + r;
        lpart[((size_t)sp*NHEAD + h)*SQ + row] = lacc[r];
      }
    }
  }
}

// ---------------- merge partial splits: float4 plain sums (shared scale) ----------------
__global__ void merge_kernel(const float* __restrict__ opart,
                             const float* __restrict__ lpart,
                             float* __restrict__ out, int S){
  int idx4 = blockIdx.x*256 + threadIdx.x;
  if (idx4 >= SQ*AHS/4) return;
  int idx = idx4*4;
  int row = idx/AHS, c = idx - row*AHS;
  int h = c >> 5;                     // 4|c and 32|AHS -> same head for all 4
  f32x4 num = {0.f,0.f,0.f,0.f};
  float den = 0.f;
  for (int s=0; s<S; ++s){
    f32x4 v = *(const f32x4*)(opart + ((size_t)s*SQ + row)*AHS + c);
    num += v;
    den += lpart[((size_t)s*NHEAD + h)*SQ + row];
  }
  float inv = 1.0f/den;
  f32x4 r = {num[0]*inv, num[1]*inv, num[2]*inv, num[3]*inv};
  *(f32x4*)(out + idx) = r;
}

extern "C" void kernel_launch(void* const* d_in, const int* in_sizes, int n_in,
                              void* d_out, int out_size, void* d_ws, size_t ws_size,
                              hipStream_t stream) {
  const float* Xh   = (const float*)d_in[0];
  const float* Xe   = (const float*)d_in[1];
  const float* mask = (const float*)d_in[2];
  const float* Wq   = (const float*)d_in[3];
  const float* bq   = (const float*)d_in[4];
  const float* Wk   = (const float*)d_in[5];
  const float* bk   = (const float*)d_in[6];
  const float* Wv   = (const float*)d_in[7];
  const float* bv   = (const float*)d_in[8];
  float* out = (float*)d_out;

  char* ws = (char*)d_ws;
  auto al256 = [](size_t b)->size_t{ return (b + 255) & ~(size_t)255; };
  size_t off = 0;
  auto alloc = [&](size_t bytes)->void*{ void* p = ws + off; off += al256(bytes); return p; };

  unsigned short* Wthi = (unsigned short*)alloc((size_t)3*DIN*AHS*2);
  unsigned short* Wtlo = (unsigned short*)alloc((size_t)3*DIN*AHS*2);
  unsigned short* EMB  = (unsigned short*)alloc((size_t)SKK*2);
  unsigned short* Qhi  = (unsigned short*)alloc((size_t)NHEAD*SQ*HD*2);
  unsigned short* Qlo  = (unsigned short*)alloc((size_t)NHEAD*SQ*HD*2);
  unsigned short* Khi  = (unsigned short*)alloc((size_t)NHEAD*SKK*HD*2);
  unsigned short* Klo  = (unsigned short*)alloc((size_t)NHEAD*SKK*HD*2);
  unsigned short* Vt   = (unsigned short*)alloc((size_t)AHS*SKK*2);
  const size_t base_end = off;

  const size_t OB = al256((size_t)SQ*AHS*4);
  const size_t MB = al256((size_t)NHEAD*SQ*4);

  auto fits = [&](int S)->bool{
    return base_end + (size_t)S*OB + (size_t)S*MB + 8192 <= ws_size;
  };

  int S = 1, direct = 0;
  if      (fits(2)) S = 2;
  else if (fits(1)) S = 1;
  else { S = 1; direct = 1; }

  char* ureg = ws + base_end;
  float *opart, *lpart;
  if (!direct){
    opart = (float*)(ureg);
    lpart = (float*)(ureg + (size_t)S*OB);
  } else {
    opart = out; lpart = (float*)ws;
  }

  {
    dim3 grid(DIN/64, AHS/64, 3);
    prep2_kernel<<<grid, 256, 0, stream>>>(Wq, Wk, Wv, mask, Wthi, Wtlo, EMB);
  }
  {
    proj5_kernel<<<384, 512, 0, stream>>>(Xh, Xe, Wthi, Wtlo,
                                          bq, bk, bv, EMB, Qhi, Qlo, Khi, Klo, Vt);
  }
  {
    int nblk = 64*NHEAD*S;
    int nkt = (SKK/64)/S;
    attn_kernel<<<nblk, 256, 0, stream>>>(Qhi, Qlo, Khi, Klo, Vt, EMB,
                                          opart, lpart, nkt, direct, nblk/8);
  }
  if (!direct){
    int n = SQ*AHS/4;
    merge_kernel<<<(n+255)/256, 256, 0, stream>>>(opart, lpart, out, S);
  }
}